// Round 10
// baseline (256.401 us; speedup 1.0000x reference)
//
#include <hip/hip_runtime.h>
#include <hip/hip_bf16.h>
#include <math.h>

#define N_NODES 50000
#define N_EDGES 800000
#define HID 128
#define N_GRAPHS 128
#define OUTC 10
#define BN_EPS 1e-5f

#define POOL_CHUNK 32
#define N_POOL_BLOCKS ((N_NODES + POOL_CHUNK - 1) / POOL_CHUNK)  // 1563

#define HB 80                 // histogram blocks per index array
#define HWORDS (N_NODES / 2)  // 25000 packed u32 words (2 x u16 bins)
#define HR_B 128              // hist_reduce block: 128 words = 256 nodes
#define HR_BLOCKS ((HWORDS + HR_B - 1) / HR_B)  // 196

#define EPAD 8                // CSR row padding (edges), multiple of 8 for guard-free inner loop
#define E_SRC_CAP (N_EDGES + N_NODES * EPAD)  // worst-case padded edge slots

#define LDA 136               // LDS row stride (ushorts): 272 B -> 16B-aligned b128, 2-way banks

typedef short short8 __attribute__((ext_vector_type(8)));
typedef float floatx4 __attribute__((ext_vector_type(4)));

template <typename T, typename F>
__device__ inline T bitcast(F f) {
    union { F a; T b; } u;
    u.a = f;
    return u.b;
}

// ---------------- LDS partial histograms (no global atomics) + W-pack tail block ----------
__global__ __launch_bounds__(1024) void hist_part_kernel(const int* __restrict__ src,
                                                         const int* __restrict__ dst,
                                                         unsigned int* __restrict__ part,
                                                         const float* __restrict__ W1,
                                                         const float* __restrict__ W2,
                                                         unsigned short* __restrict__ Wp) {
    if (blockIdx.x == 2 * HB) {
        // pack W into MFMA B-frag order: lane holds B[k=quad*8+j][n=lane&15], j in [0,8)
        for (int q = threadIdx.x; q < 4096; q += 1024) {  // 2 mats x 32 tiles x 64 lanes
            int wi = q >> 11;
            const float* __restrict__ W = wi ? W2 : W1;
            int t2 = q & 2047;
            int tile = t2 >> 6, lane = t2 & 63;
            int kc = tile >> 3, nt = tile & 7;
            int n = lane & 15, quad = lane >> 4;
            unsigned short v[8];
#pragma unroll
            for (int j = 0; j < 8; j++) {
                int k = kc * 32 + quad * 8 + j;
                v[j] = __hip_bfloat16_raw(__float2bfloat16(W[k * HID + nt * 16 + n])).x;
            }
            *(uint4*)&Wp[(size_t)q * 8] = *(uint4*)v;
        }
        return;
    }
    __shared__ unsigned int h[HWORDS];  // 100 KB
    for (int i = threadIdx.x; i < HWORDS; i += 1024) h[i] = 0;
    __syncthreads();
    int half = (blockIdx.x >= HB) ? 1 : 0;
    const int* __restrict__ idx = half ? dst : src;
    int b = blockIdx.x - half * HB;
    for (int e = b * 1024 + threadIdx.x; e < N_EDGES; e += HB * 1024) {
        int v = idx[e];
        atomicAdd(&h[v >> 1], 1u << ((v & 1) << 4));  // LDS atomic, CU-local
    }
    __syncthreads();
    unsigned int* __restrict__ out = part + (size_t)blockIdx.x * HWORDS;
    for (int i = threadIdx.x; i < HWORDS; i += 1024) out[i] = h[i];
}

// ---------------- fused: reduce partials + inv_sqrt + CSR offsets + pad-fill ------------
// Per block (128 threads = 256 nodes): sum over HB partials (rewriting dst half in place to
// per-(block,node) exclusive prefixes for csr_fill), intra-block scan of padded counts,
// arrival-order block base via one atomicAdd, write row_ptr/row_end, stamp pad slots.
// CSR slabs are arrival-ordered (NOT node-ordered) -> agg must use row_end, not row_ptr[n+1].
__global__ __launch_bounds__(HR_B) void hist_reduce_scan_kernel(unsigned int* __restrict__ part,
                                                                float* __restrict__ inv_out,
                                                                float* __restrict__ inv_in,
                                                                int* __restrict__ row_ptr,
                                                                int* __restrict__ row_end,
                                                                int* __restrict__ edge_src,
                                                                int* __restrict__ counter) {
    int t = threadIdx.x;
    int w = blockIdx.x * HR_B + t;
    int raw0 = 0, raw1 = 0, p0 = 0, p1 = 0;
    if (w < HWORDS) {
        unsigned int s = 0, d = 0;
        for (int b = 0; b < HB; b++) {
            s += part[(size_t)b * HWORDS + w];
            unsigned int c = part[(size_t)(b + HB) * HWORDS + w];
            part[(size_t)(b + HB) * HWORDS + w] = d;  // exclusive prefix over blocks
            d += c;
        }
        int i0 = w * 2, i1 = i0 + 1;
        int so0 = (int)(s & 0xFFFFu), so1 = (int)(s >> 16);
        raw0 = (int)(d & 0xFFFFu);
        raw1 = (int)(d >> 16);
        inv_out[i0] = rsqrtf(fmaxf((float)so0, 1.0f));
        inv_out[i1] = rsqrtf(fmaxf((float)so1, 1.0f));
        inv_in[i0] = rsqrtf(fmaxf((float)raw0, 1.0f));
        inv_in[i1] = rsqrtf(fmaxf((float)raw1, 1.0f));
        p0 = (raw0 + EPAD - 1) & ~(EPAD - 1);
        p1 = (raw1 + EPAD - 1) & ~(EPAD - 1);
    }
    // intra-block exclusive scan over the 256 padded counts (2 per thread)
    __shared__ int sc[HR_B];
    __shared__ int base_sh;
    int tsum = p0 + p1;
    sc[t] = tsum;
    __syncthreads();
    for (int o = 1; o < HR_B; o <<= 1) {
        int u = (t >= o) ? sc[t - o] : 0;
        __syncthreads();
        sc[t] += u;
        __syncthreads();
    }
    if (t == HR_B - 1) base_sh = atomicAdd(counter, sc[t]);  // arrival-order block base
    __syncthreads();
    int ex = base_sh + sc[t] - tsum;
    if (w < HWORDS) {
        int i0 = w * 2, i1 = i0 + 1;
        int st0 = ex, st1 = ex + p0;
        row_ptr[i0] = st0;
        row_end[i0] = st0 + p0;
        row_ptr[i1] = st1;
        row_end[i1] = st1 + p1;
        for (int p = st0 + raw0; p < st0 + p0; p++) edge_src[p] = N_NODES;  // pad slots
        for (int p = st1 + raw1; p < st1 + p1; p++) edge_src[p] = N_NODES;
    }
}

// ---------------- CSR fill, atomic-free (disjoint from pad slots) ----------------
__global__ __launch_bounds__(1024) void csr_fill_kernel(const int* __restrict__ src,
                                                        const int* __restrict__ dst,
                                                        const unsigned int* __restrict__ part,
                                                        const int* __restrict__ row_ptr,
                                                        int* __restrict__ edge_src) {
    __shared__ unsigned int loc[HWORDS];  // 100 KB: packed u16 running intra-bucket slots
    int b = blockIdx.x;
    const unsigned int* __restrict__ off = part + (size_t)(b + HB) * HWORDS;
    for (int i = threadIdx.x; i < HWORDS; i += 1024) loc[i] = off[i];
    __syncthreads();
    for (int e = b * 1024 + threadIdx.x; e < N_EDGES; e += HB * 1024) {
        int d = dst[e];
        unsigned int old = atomicAdd(&loc[d >> 1], 1u << ((d & 1) << 4));  // LDS atomic
        int local = (d & 1) ? (int)(old >> 16) : (int)(old & 0xFFFFu);
        edge_src[row_ptr[d] + local] = src[e];  // plain scattered store
    }
}

// ---------------- Y[r][:] = bf16( (scale[r]*X[r][:]) @ W )  via MFMA bf16 ----------------
// block: 64 rows x 128 cols, 4 waves x (16 rows x 128 cols); emits dummy zero row N_NODES.
// IN_BF16: input is bf16[N][128] instead of fp32.
template <int IN_BF16>
__global__ __launch_bounds__(256) void matmul_kernel(const void* __restrict__ Xin,
                                                     const float* __restrict__ scale,
                                                     const unsigned short* __restrict__ Wp,
                                                     __hip_bfloat16* __restrict__ Y) {
    __shared__ unsigned short xs[64 * LDA];  // 17 KB bf16, padded rows
    int tid = threadIdx.x;
    int row0 = blockIdx.x * 64;

    if (IN_BF16) {
        const unsigned int* __restrict__ X = (const unsigned int*)Xin;  // 2 bf16/word
        for (int j = 0; j < 4; j++) {
            int idx8 = j * 256 + tid;          // 8-elt group in 64x128 tile
            int r = idx8 >> 4;
            int col = (idx8 & 15) * 8;
            int rg = row0 + r;
            unsigned short o[8] = {};
            if (rg < N_NODES) {
                uint4 u = *(const uint4*)&X[(size_t)rg * (HID / 2) + col / 2];
                float sc = scale[rg];
                unsigned int uw[4] = {u.x, u.y, u.z, u.w};
#pragma unroll
                for (int q = 0; q < 4; q++) {
                    float lo = __uint_as_float(uw[q] << 16) * sc;
                    float hi = __uint_as_float(uw[q] & 0xFFFF0000u) * sc;
                    o[q * 2]     = __hip_bfloat16_raw(__float2bfloat16(lo)).x;
                    o[q * 2 + 1] = __hip_bfloat16_raw(__float2bfloat16(hi)).x;
                }
            }
            *(uint4*)&xs[r * LDA + col] = *(uint4*)o;
        }
    } else {
        const float* __restrict__ X = (const float*)Xin;
        for (int j = 0; j < 8; j++) {
            int idx4 = j * 256 + tid;          // float4 index in 64x128 tile
            int r = idx4 >> 5;
            int col = (idx4 & 31) * 4;
            int rg = row0 + r;
            float4 v = make_float4(0.f, 0.f, 0.f, 0.f);
            if (rg < N_NODES) {
                v = *(const float4*)&X[(size_t)rg * HID + col];
                float sc = scale[rg];
                v.x *= sc; v.y *= sc; v.z *= sc; v.w *= sc;
            }
            unsigned short o[4];
            o[0] = __hip_bfloat16_raw(__float2bfloat16(v.x)).x;
            o[1] = __hip_bfloat16_raw(__float2bfloat16(v.y)).x;
            o[2] = __hip_bfloat16_raw(__float2bfloat16(v.z)).x;
            o[3] = __hip_bfloat16_raw(__float2bfloat16(v.w)).x;
            *(ushort4*)&xs[r * LDA + col] = *(ushort4*)o;
        }
    }
    __syncthreads();

    int wave = tid >> 6, lane = tid & 63;
    int m = lane & 15, quad = lane >> 4;
    int rowl = wave * 16;  // wave's 16-row slice within tile

    short8 a[4];
#pragma unroll
    for (int kc = 0; kc < 4; kc++)
        a[kc] = bitcast<short8>(*(const uint4*)&xs[(rowl + m) * LDA + kc * 32 + quad * 8]);

    floatx4 acc[8];
#pragma unroll
    for (int nt = 0; nt < 8; nt++) acc[nt] = (floatx4){0.f, 0.f, 0.f, 0.f};

#pragma unroll
    for (int nt = 0; nt < 8; nt++) {
#pragma unroll
        for (int kc = 0; kc < 4; kc++) {
            short8 bfr = bitcast<short8>(
                *(const uint4*)&Wp[((size_t)(kc * 8 + nt) * 64 + lane) * 8]);
            acc[nt] = __builtin_amdgcn_mfma_f32_16x16x32_bf16(a[kc], bfr, acc[nt], 0, 0, 0);
        }
    }

    // C/D layout: col = lane&15, row = quad*4 + reg  [verified m89]
#pragma unroll
    for (int nt = 0; nt < 8; nt++) {
#pragma unroll
        for (int i = 0; i < 4; i++) {
            int rg = row0 + rowl + quad * 4 + i;
            if (rg < N_NODES + 1) {
                Y[(size_t)rg * HID + nt * 16 + m] = __float2bfloat16(acc[nt][i]);
            }
        }
    }
}

// ---------------- CSR gather-accumulate over bf16 Y (fp32 accumulate) ----------------
// OUT_BF16: emit bf16 rows (layer-1 -> matmul2 handoff) vs fp32 (layer-2 -> pool).
template <int OUT_BF16>
__global__ __launch_bounds__(256) void agg_kernel(const __hip_bfloat16* __restrict__ Y,
                                                  const int* __restrict__ edge_src,
                                                  const int* __restrict__ row_ptr,
                                                  const int* __restrict__ row_end,
                                                  const float* __restrict__ inv_in,
                                                  const float* __restrict__ bias,
                                                  void* __restrict__ Xout) {
    const uint4* __restrict__ Yq = (const uint4*)Y;  // 8 bf16 per uint4
    int wave = threadIdx.x >> 6;
    int lane = threadIdx.x & 63;
    int n = blockIdx.x * 4 + wave;
    if (n >= N_NODES) return;
    int beg = row_ptr[n], end = row_end[n];  // slab length multiple of 8
    int esub = lane >> 4;   // which of 4 concurrent edges
    int f16  = lane & 15;   // feature quad: feats f16*8 .. f16*8+7
    float acc[8] = {};
    for (int base = beg; base < end; base += 64) {
        int mm = min(64, end - base);  // multiple of 8
        int idx = (lane < mm) ? edge_src[base + lane] : N_NODES;
        for (int j = 0; j < mm; j += 8) {
            int s0 = __shfl(idx, j + esub);
            int s1 = __shfl(idx, j + 4 + esub);
            uint4 u0 = Yq[s0 * (HID / 8) + f16];
            uint4 u1 = Yq[s1 * (HID / 8) + f16];
            acc[0] += __uint_as_float(u0.x << 16); acc[1] += __uint_as_float(u0.x & 0xFFFF0000u);
            acc[2] += __uint_as_float(u0.y << 16); acc[3] += __uint_as_float(u0.y & 0xFFFF0000u);
            acc[4] += __uint_as_float(u0.z << 16); acc[5] += __uint_as_float(u0.z & 0xFFFF0000u);
            acc[6] += __uint_as_float(u0.w << 16); acc[7] += __uint_as_float(u0.w & 0xFFFF0000u);
            acc[0] += __uint_as_float(u1.x << 16); acc[1] += __uint_as_float(u1.x & 0xFFFF0000u);
            acc[2] += __uint_as_float(u1.y << 16); acc[3] += __uint_as_float(u1.y & 0xFFFF0000u);
            acc[4] += __uint_as_float(u1.z << 16); acc[5] += __uint_as_float(u1.z & 0xFFFF0000u);
            acc[6] += __uint_as_float(u1.w << 16); acc[7] += __uint_as_float(u1.w & 0xFFFF0000u);
        }
    }
#pragma unroll
    for (int i = 0; i < 8; i++) {
        acc[i] += __shfl_xor(acc[i], 16);
        acc[i] += __shfl_xor(acc[i], 32);
    }
    if (lane < 16) {
        float si = inv_in[n];
        int f0 = f16 * 8;
        float4 b0 = *(const float4*)&bias[f0];
        float4 b1 = *(const float4*)&bias[f0 + 4];
        float o[8];
        o[0] = fmaxf(acc[0] * si + b0.x, 0.f);
        o[1] = fmaxf(acc[1] * si + b0.y, 0.f);
        o[2] = fmaxf(acc[2] * si + b0.z, 0.f);
        o[3] = fmaxf(acc[3] * si + b0.w, 0.f);
        o[4] = fmaxf(acc[4] * si + b1.x, 0.f);
        o[5] = fmaxf(acc[5] * si + b1.y, 0.f);
        o[6] = fmaxf(acc[6] * si + b1.z, 0.f);
        o[7] = fmaxf(acc[7] * si + b1.w, 0.f);
        if (OUT_BF16) {
            unsigned short ob[8];
#pragma unroll
            for (int i = 0; i < 8; i++)
                ob[i] = __hip_bfloat16_raw(__float2bfloat16(o[i])).x;
            *(uint4*)&((unsigned short*)Xout)[(size_t)n * HID + f0] = *(uint4*)ob;
        } else {
            float* Xf = (float*)Xout;
            *(float4*)&Xf[(size_t)n * HID + f0] = make_float4(o[0], o[1], o[2], o[3]);
            *(float4*)&Xf[(size_t)n * HID + f0 + 4] = make_float4(o[4], o[5], o[6], o[7]);
        }
    }
}

// ---------------- SumPooling: chunked segment-sum over sorted gid ----------------
__global__ __launch_bounds__(64) void pool_kernel(const float* __restrict__ X,
                                                  const int* __restrict__ gid,
                                                  float* __restrict__ emb) {
    int lane = threadIdx.x;
    int n0 = blockIdx.x * POOL_CHUNK;
    int n1 = min(n0 + POOL_CHUNK, N_NODES);
    if (n0 >= N_NODES) return;
    int g_cur = gid[n0];
    float ax = 0.f, ay = 0.f;
    for (int n = n0; n < n1; n++) {
        int g = gid[n];
        if (g != g_cur) {
            atomicAdd(&emb[g_cur * HID + lane * 2], ax);
            atomicAdd(&emb[g_cur * HID + lane * 2 + 1], ay);
            ax = 0.f; ay = 0.f;
            g_cur = g;
        }
        float2 v = *(const float2*)&X[(size_t)n * HID + lane * 2];
        ax += v.x;
        ay += v.y;
    }
    atomicAdd(&emb[g_cur * HID + lane * 2], ax);
    atomicAdd(&emb[g_cur * HID + lane * 2 + 1], ay);
}

// ---------------- fused BN-stats + fc1 + fc2 + log_softmax ----------------
__global__ __launch_bounds__(128) void head_fused_kernel(const float* __restrict__ emb,
                                                         const float* __restrict__ gamma,
                                                         const float* __restrict__ beta,
                                                         const float* __restrict__ fc1_w,
                                                         const float* __restrict__ fc1_b,
                                                         const float* __restrict__ fc2_w,
                                                         const float* __restrict__ fc2_b,
                                                         float* __restrict__ out) {
    int r = blockIdx.x, f = threadIdx.x;
    float s = 0.f;
    for (int row = 0; row < N_GRAPHS; row++) s += emb[row * HID + f];
    float mu = s * (1.f / N_GRAPHS);
    float v = 0.f;
    for (int row = 0; row < N_GRAPHS; row++) {
        float d = emb[row * HID + f] - mu;
        v += d * d;
    }
    v *= (1.f / N_GRAPHS);
    float sc = gamma[f] * rsqrtf(v + BN_EPS);
    float sh = beta[f] - mu * sc;

    __shared__ float xr[HID];
    xr[f] = emb[r * HID + f] * sc + sh;
    __syncthreads();
    float acc = fc1_b[f];
    for (int k = 0; k < HID; k++) acc += xr[k] * fc1_w[k * HID + f];
    __shared__ float hr[HID];
    hr[f] = fmaxf(acc, 0.f);
    __syncthreads();

    __shared__ float logits[OUTC];
    __shared__ float mstat[2];
    if (f < OUTC) {
        float a = fc2_b[f];
        for (int k = 0; k < HID; k++) a += hr[k] * fc2_w[k * OUTC + f];
        logits[f] = a;
    }
    __syncthreads();
    if (f == 0) {
        float m = logits[0];
        for (int o = 1; o < OUTC; o++) m = fmaxf(m, logits[o]);
        float sum = 0.f;
        for (int o = 0; o < OUTC; o++) sum += expf(logits[o] - m);
        mstat[0] = m;
        mstat[1] = logf(sum);
    }
    __syncthreads();
    if (f < OUTC) out[r * OUTC + f] = logits[f] - mstat[0] - mstat[1];
}

extern "C" void kernel_launch(void* const* d_in, const int* in_sizes, int n_in,
                              void* d_out, int out_size, void* d_ws, size_t ws_size,
                              hipStream_t stream) {
    const float* n_feat = (const float*)d_in[0];
    const int*   src    = (const int*)d_in[1];
    const int*   dst    = (const int*)d_in[2];
    const int*   gid    = (const int*)d_in[3];
    const float* W1     = (const float*)d_in[4];
    const float* b1     = (const float*)d_in[5];
    const float* W2     = (const float*)d_in[6];
    const float* b2     = (const float*)d_in[7];
    const float* gamma  = (const float*)d_in[8];
    const float* beta   = (const float*)d_in[9];
    const float* fc1_w  = (const float*)d_in[10];
    const float* fc1_b  = (const float*)d_in[11];
    const float* fc2_w  = (const float*)d_in[12];
    const float* fc2_b  = (const float*)d_in[13];

    char* wsb = (char*)d_ws;
    size_t off = 0;
    auto alloc = [&](size_t bytes) -> void* {
        void* p = wsb + off;
        off += (bytes + 255) & ~(size_t)255;
        return p;
    };
    int*   row_ptr = (int*)alloc((size_t)N_NODES * 4);
    int*   row_end = (int*)alloc((size_t)N_NODES * 4);
    int*   e_src   = (int*)alloc((size_t)E_SRC_CAP * 4);
    float* inv_out = (float*)alloc((size_t)N_NODES * 4);
    float* inv_in  = (float*)alloc((size_t)N_NODES * 4);
    // ybuf doubles as: partial histograms (2*HB*HWORDS u32 = 16 MB), then bf16 Y incl. dummy row
    void*  ybuf    = alloc((size_t)2 * HB * HWORDS * 4);
    float* X       = (float*)alloc((size_t)N_NODES * HID * 4);        // fp32 (agg2 -> pool)
    unsigned short* Xb = (unsigned short*)alloc((size_t)N_NODES * HID * 2);  // bf16 (agg1 -> matmul2)
    unsigned short* Wp = (unsigned short*)alloc((size_t)2 * 32 * 64 * 8 * 2);  // 64 KB packed W1+W2
    int*   counter = (int*)alloc(256);

    unsigned int*   part = (unsigned int*)ybuf;
    __hip_bfloat16* Y    = (__hip_bfloat16*)ybuf;  // (N_NODES+1) x HID bf16 = 12.8 MB + 256 B

    float* emb_out = (float*)d_out;                // [128,128]
    float* lsm_out = emb_out + N_GRAPHS * HID;     // [128,10]

    hipMemsetAsync(emb_out, 0, (size_t)N_GRAPHS * HID * 4, stream);
    hipMemsetAsync(counter, 0, 4, stream);

    hist_part_kernel<<<2 * HB + 1, 1024, 0, stream>>>(src, dst, part, W1, W2, Wp);
    hist_reduce_scan_kernel<<<HR_BLOCKS, HR_B, 0, stream>>>(part, inv_out, inv_in, row_ptr,
                                                            row_end, e_src, counter);
    csr_fill_kernel<<<HB, 1024, 0, stream>>>(src, dst, part, row_ptr, e_src);

    // layer 1 (MFMA bf16)
    matmul_kernel<0><<<(N_NODES + 64) / 64, 256, 0, stream>>>(n_feat, inv_out, Wp, Y);
    agg_kernel<1><<<(N_NODES + 3) / 4, 256, 0, stream>>>(Y, e_src, row_ptr, row_end,
                                                         inv_in, b1, Xb);
    // layer 2 (bf16 input handoff)
    matmul_kernel<1><<<(N_NODES + 64) / 64, 256, 0, stream>>>(Xb, inv_out,
                                                              Wp + (size_t)32 * 64 * 8, Y);
    agg_kernel<0><<<(N_NODES + 3) / 4, 256, 0, stream>>>(Y, e_src, row_ptr, row_end,
                                                         inv_in, b2, X);

    // pooling -> embedding output
    pool_kernel<<<N_POOL_BLOCKS, 64, 0, stream>>>(X, gid, emb_out);
    // fused head
    head_fused_kernel<<<N_GRAPHS, HID, 0, stream>>>(emb_out, gamma, beta, fc1_w, fc1_b,
                                                    fc2_w, fc2_b, lsm_out);
}